// Round 24
// baseline (107.101 us; speedup 1.0000x reference)
//
#include <hip/hip_runtime.h>
#include <hip/hip_bf16.h>

// SDPA, causal, b=16 t=2048 d=64. Outputs FP32: d_out = [ out | sm_qk ].
// R24 = R23 + K B-FRAGS DIRECT FROM GLOBAL (bf16, pre-converted by prologue):
//  - phase 1 is now BARRIER-FREE: per-wave loop, frags loaded straight from
//    global (L1-resident 16KB tiles, 4-wave reuse), 2-deep reg pipeline.
//    (R6's failure mode was per-wave fp32 cvt -- gone since R23.)
//  - phase 2 drops Khi staging entirely: kf loaded at round top (older than
//    the round's stores -> in-order vmcnt costs nothing), used after
//    rowStore+PV. V staging (waves 4-7) unchanged.
//  - LDS 63 KB (Vt[3]+Pf[2]+lS); __launch_bounds__(512,4) caps VGPR at 128
//    to guarantee 2 blocks/CU.
// Bit-identical math vs R23 -> absmax must stay exactly 0.015625.
// R23 base: prologue cvt_kv (K,V fp32->bf16 in d_ws); 8-wave blocks;
// T15 pipeline; Q-side-compensated QK^T; fp32 Pf[2]; vectorized 1KB P-stores;
// lgkm-only barriers; mirror-band zero-fill; XCD clustering; pairing (c,31-c).

#define BATCHES 16
#define SEQ 2048
#define DIM 64
#define QB 64
#define KT 64
#define NQB (SEQ / QB) /* 32 */
#define VLD 72
#define PFLD 68
#define NEL ((size_t)BATCHES * SEQ * DIM) /* 2M elems per tensor */

#define BAR() do { asm volatile("s_waitcnt lgkmcnt(0)" ::: "memory"); \
                   __builtin_amdgcn_s_barrier(); } while (0)

typedef __attribute__((ext_vector_type(8))) short bf16x8;
typedef __attribute__((ext_vector_type(4))) short short4v;
typedef __attribute__((ext_vector_type(4))) float f32x4;

static __device__ __forceinline__ short f2bf(float f) {
    return __builtin_bit_cast(short, __float2bfloat16(f));
}
static __device__ __forceinline__ float bf2f(short s) {
    unsigned int u = ((unsigned int)(unsigned short)s) << 16;
    return __builtin_bit_cast(float, u);
}
static __device__ __forceinline__ void split8(f32x4 a, f32x4 b, float sc,
                                              bf16x8& hh, bf16x8& ll) {
#pragma unroll
    for (int e = 0; e < 4; ++e) {
        float x = a[e] * sc; short hb = f2bf(x);
        hh[e] = hb; ll[e] = f2bf(x - bf2f(hb));
    }
#pragma unroll
    for (int e = 0; e < 4; ++e) {
        float x = b[e] * sc; short hb = f2bf(x);
        hh[4 + e] = hb; ll[4 + e] = f2bf(x - bf2f(hb));
    }
}

// ---------- prologue: K,V fp32 -> bf16 into d_ws (once) ----------
__global__ __launch_bounds__(256) void cvt_kv(
    const float* __restrict__ Kg, const float* __restrict__ Vg,
    short* __restrict__ KVh)
{
    const size_t idx = ((size_t)blockIdx.x * 256 + threadIdx.x) * 8;
    const float* src = (idx < NEL) ? (Kg + idx) : (Vg + (idx - NEL));
    f32x4 a = *(const f32x4*)src;
    f32x4 b = *(const f32x4*)(src + 4);
    bf16x8 r;
#pragma unroll
    for (int e = 0; e < 4; ++e) { r[e] = f2bf(a[e]); r[4 + e] = f2bf(b[e]); }
    *(bf16x8*)&KVh[idx] = r;
}

// LDS (bytes): Vt[3] 27648 @0 | Pf[2] 34816 @27648 | lS 512 @62464 = 62976
#define SMEM_BYTES 62976

__global__ __launch_bounds__(512, 4) void sdpa_fused(
    const float* __restrict__ Qg, const short* __restrict__ Khg,
    const short* __restrict__ Vhg, float* __restrict__ Og, float* __restrict__ Pg)
{
    const int i = blockIdx.x;
    const int g = i & 7;
    const int j = i >> 3;             // 0..63
    const int b = 2 * g + (j >> 5);
    const int jj = j & 31;
    const int qb = (j < 32) ? jj : (31 - jj);   // sum-balanced pairing
    const int q0 = qb * QB;

    const int tid = threadIdx.x;
    const int lane = tid & 63;
    const int wave = tid >> 6;        // 0..7
    const int wr = wave & 3;          // row band: rows wr*16..wr*16+15
    const int h  = wave >> 2;         // col half
    const int n0 = 2 * h;
    const int lo = lane & 15;
    const int hi = lane >> 4;
    const bool vStager = (wave >= 4);
    const int stid = tid & 255;       // 0..255 within role group
    const int sc_ = (stid & 15) * 4;
    const int vr = (stid >> 4) * 4;

    __shared__ __align__(16) char smem[SMEM_BYTES];
    short (*Vt)[DIM * VLD]  = reinterpret_cast<short (*)[DIM * VLD]>(smem);           // [3]
    float (*Pf)[QB * PFLD]  = reinterpret_cast<float (*)[QB * PFLD]>(smem + 27648);   // [2]
    float (*lS)[QB]         = reinterpret_cast<float (*)[QB]>(smem + 62464);          // [2]

    const float* qB = Qg + (size_t)b * SEQ * DIM;
    const short* kB = Khg + (size_t)b * SEQ * DIM;
    const short* vB = Vhg + (size_t)b * SEQ * DIM;

    bf16x8 qa0h, qa0l, qa1h, qa1l;
    {
        const float* qr = &qB[(size_t)(q0 + wr * 16 + lo) * DIM + hi * 8];
        split8(*(const f32x4*)qr,        *(const f32x4*)(qr + 4),  0.125f, qa0h, qa0l);
        split8(*(const f32x4*)(qr + 32), *(const f32x4*)(qr + 36), 0.125f, qa1h, qa1l);
    }

    const int nkt = qb + 1;

    // K B-frag direct load: d[2nn+s] = K[kt*64 + 16(n0+nn) + lo][32s + hi*8 ..+7]
    auto ldK = [&](bf16x8* d, int kt) {
#pragma unroll
        for (int nn = 0; nn < 2; ++nn) {
            const short* base = &kB[(size_t)(kt * KT + 16 * (n0 + nn) + lo) * DIM + hi * 8];
            d[2 * nn]     = *(const bf16x8*)base;
            d[2 * nn + 1] = *(const bf16x8*)(base + 32);
        }
    };

    // mirror-band zero-fill coords: band (31-qb) of our own batch
    const int r16z = tid >> 4;        // 0..31
    const int c4z = (tid & 15) * 4;
    float* zrow0 = &Pg[((size_t)(b * SEQ) + (NQB - 1 - qb) * QB + r16z) * SEQ + c4z];
    float* zrow1 = zrow0 + (size_t)32 * SEQ;

    // ============ phase 1: l partial sums — BARRIER-FREE, per-wave ============
    float rl[4] = {0.f, 0.f, 0.f, 0.f};
    {
        auto tile = [&](const bf16x8* kf, int kt) {
#pragma unroll
            for (int nn = 0; nn < 2; ++nn) {
                const int n = n0 + nn;
                if (kt == qb && n > wr) continue;     // wave-uniform skip
                f32x4 acc = {0.f, 0.f, 0.f, 0.f};
                __builtin_amdgcn_s_setprio(1);
                acc = __builtin_amdgcn_mfma_f32_16x16x32_bf16(qa0h, kf[2 * nn], acc, 0, 0, 0);
                acc = __builtin_amdgcn_mfma_f32_16x16x32_bf16(qa1h, kf[2 * nn + 1], acc, 0, 0, 0);
                __builtin_amdgcn_s_setprio(0);
                if (kt < qb || n < wr) {              // fully unmasked
#pragma unroll
                    for (int jx = 0; jx < 4; ++jx) rl[jx] += __expf(acc[jx]);
                } else {                              // diagonal 16x16 group
                    const int col = 16 * n + lo;
#pragma unroll
                    for (int jx = 0; jx < 4; ++jx)
                        if (col <= wr * 16 + hi * 4 + jx) rl[jx] += __expf(acc[jx]);
                }
            }
        };
        bf16x8 kfa[4], kfb[4];
        ldK(kfa, 0);
        int kt = 0;
        while (true) {
            if (kt + 1 <= qb) ldK(kfb, kt + 1);
            tile(kfa, kt);
            if (++kt > qb) break;
            if (kt + 1 <= qb) ldK(kfa, kt + 1);
            tile(kfb, kt);
            if (++kt > qb) break;
        }
    }
    // merge the two col-half partials -> il
#pragma unroll
    for (int m = 1; m <= 8; m <<= 1)
#pragma unroll
        for (int jx = 0; jx < 4; ++jx) rl[jx] += __shfl_xor(rl[jx], m, 16);
    if (lo == 0) {
#pragma unroll
        for (int jx = 0; jx < 4; ++jx)
            lS[h][wr * 16 + hi * 4 + jx] = rl[jx];
    }
    BAR();
    float il[4];
#pragma unroll
    for (int jx = 0; jx < 4; ++jx) {
        const int row = wr * 16 + hi * 4 + jx;
        il[jx] = 1.0f / (lS[0][row] + lS[1][row]);
    }

    // ===== phase 2: QKT(direct-K) -> Pf, vectorized row-store + PV pipelined ==
    f32x4 o2[2];
#pragma unroll
    for (int nn = 0; nn < 2; ++nn) { o2[nn][0] = 0.f; o2[nn][1] = 0.f; o2[nn][2] = 0.f; o2[nn][3] = 0.f; }

    auto loadV = [&](short4v* vp, int kt) {
#pragma unroll
        for (int ii = 0; ii < 4; ++ii)
            vp[ii] = *(const short4v*)&vB[(size_t)(kt * KT + vr + ii) * DIM + sc_];
    };
    auto stageVt = [&](int buf, const short4v* vp) {
#pragma unroll
        for (int e = 0; e < 4; ++e) {   // 4x4 register transpose, no cvt
            short4v tv;
#pragma unroll
            for (int ii = 0; ii < 4; ++ii) tv[ii] = vp[ii][e];
            *(short4v*)&Vt[buf][(sc_ + e) * VLD + vr] = tv;
        }
    };
    // VECTORIZED P row-store: lane covers rows wave*8+{rr,rr+4}, 16B each
    auto rowStore = [&](int pbuf, int kt) {
        const int rr = lane >> 4;          // 0..3
        const int cc = (lane & 15) * 4;    // 16B-aligned col offset
        float* dst0 = &Pg[((size_t)(b * SEQ) + q0 + wave * 8 + rr) * SEQ + kt * KT + cc];
        *(f32x4*)dst0 = *(const f32x4*)&Pf[pbuf][(wave * 8 + rr) * PFLD + cc];
        *(f32x4*)(dst0 + (size_t)4 * SEQ) =
            *(const f32x4*)&Pf[pbuf][(wave * 8 + 4 + rr) * PFLD + cc];
    };
    // PV from Pf[pbuf] (fp32 -> bf16 frags) against Vt[vbuf]
    auto pvStep = [&](int pbuf, int vbuf) {
        const float* pr = &Pf[pbuf][(wr * 16 + lo) * PFLD + hi * 8];
        f32x4 a = *(const f32x4*)pr, c2 = *(const f32x4*)(pr + 4);
        f32x4 d = *(const f32x4*)(pr + 32), e2 = *(const f32x4*)(pr + 36);
        bf16x8 pa0, pa1;
#pragma unroll
        for (int e = 0; e < 4; ++e) {
            pa0[e] = f2bf(a[e]); pa0[4 + e] = f2bf(c2[e]);
            pa1[e] = f2bf(d[e]); pa1[4 + e] = f2bf(e2[e]);
        }
        __builtin_amdgcn_s_setprio(1);
#pragma unroll
        for (int nn = 0; nn < 2; ++nn) {
            const int n = n0 + nn;
            bf16x8 vb0 = *(const bf16x8*)&Vt[vbuf][(16 * n + lo) * VLD + hi * 8];
            bf16x8 vb1 = *(const bf16x8*)&Vt[vbuf][(16 * n + lo) * VLD + 32 + hi * 8];
            o2[nn] = __builtin_amdgcn_mfma_f32_16x16x32_bf16(pa0, vb0, o2[nn], 0, 0, 0);
            o2[nn] = __builtin_amdgcn_mfma_f32_16x16x32_bf16(pa1, vb1, o2[nn], 0, 0, 0);
        }
        __builtin_amdgcn_s_setprio(0);
    };

    {
        short4v vp[4];
        if (vStager) {
            loadV(vp, 0); stageVt(0, vp);
            if (nkt > 1) loadV(vp, 1);
        }
        BAR();

        int vstg = 1, vprev = 2;
        for (int kt = 0; kt < nkt; ++kt) {
            const int pcur = kt & 1;
            bf16x8 kf[4];
            ldK(kf, kt);                   // issue early; used after rowStore/PV
            // mirror-band zero tile (1/round, kt<qb): 2 dwordx4/thread
            if (kt < qb) {
                const int zt = (NQB - qb) + kt;
                const f32x4 zv = {0.f, 0.f, 0.f, 0.f};
                *(f32x4*)&zrow0[zt * KT] = zv;
                *(f32x4*)&zrow1[zt * KT] = zv;
            }
            if (kt + 1 < nkt && vStager) {
                stageVt(vstg, vp);
                if (kt + 2 < nkt) loadV(vp, kt + 2);
            }
            // ---- tile kt-1: vectorized row-store + PV (inputs ready at start)
            if (kt > 0) {
                rowStore(pcur ^ 1, kt - 1);
                pvStep(pcur ^ 1, vprev);
            }
            // ---- QKT(kt) (Q-side compensated, direct-K): P = exp(S)*il ----
#pragma unroll
            for (int nn = 0; nn < 2; ++nn) {
                const int n = n0 + nn;
                const bool fm = (kt == qb) && (n > wr);   // wave-uniform
                f32x4 acc = {0.f, 0.f, 0.f, 0.f};
                if (!fm) {
                    __builtin_amdgcn_s_setprio(1);
                    acc = __builtin_amdgcn_mfma_f32_16x16x32_bf16(qa0h, kf[2 * nn], acc, 0, 0, 0);
                    acc = __builtin_amdgcn_mfma_f32_16x16x32_bf16(qa1h, kf[2 * nn + 1], acc, 0, 0, 0);
                    acc = __builtin_amdgcn_mfma_f32_16x16x32_bf16(qa0l, kf[2 * nn], acc, 0, 0, 0);
                    acc = __builtin_amdgcn_mfma_f32_16x16x32_bf16(qa1l, kf[2 * nn + 1], acc, 0, 0, 0);
                    __builtin_amdgcn_s_setprio(0);
                }
                const int col = 16 * n + lo;
#pragma unroll
                for (int jx = 0; jx < 4; ++jx) {
                    const int row = wr * 16 + hi * 4 + jx;
                    const float p = (!fm && (kt < qb || col <= row)) ? __expf(acc[jx]) * il[jx] : 0.f;
                    Pf[pcur][row * PFLD + col] = p;
                }
            }
            BAR();
            vprev = (vprev == 2) ? 0 : vprev + 1;
            vstg  = (vstg  == 2) ? 0 : vstg  + 1;
        }
        // ---- epilogue: tile nkt-1 store + PV (after the loop's final BAR) ----
        {
            const int pl = (nkt - 1) & 1;
            const int vl = (nkt - 1) % 3;
            rowStore(pl, nkt - 1);
            pvStep(pl, vl);
        }
    }

    // ---- O (already normalized; own col half), fp32 ----
    {
        float* og = &Og[((size_t)(b * SEQ) + q0 + wr * 16 + hi * 4) * DIM + lo];
#pragma unroll
        for (int jx = 0; jx < 4; ++jx)
#pragma unroll
            for (int nn = 0; nn < 2; ++nn)
                og[jx * DIM + (n0 + nn) * 16] = o2[nn][jx];
    }
}

extern "C" void kernel_launch(void* const* d_in, const int* in_sizes, int n_in,
                              void* d_out, int out_size, void* d_ws, size_t ws_size,
                              hipStream_t stream) {
    const float* q = (const float*)d_in[0];
    const float* k = (const float*)d_in[1];
    const float* v = (const float*)d_in[2];
    float* out  = (float*)d_out;                        // [B,T,D] fp32
    float* smqk = out + (size_t)BATCHES * SEQ * DIM;    // [B,T,T] fp32
    short* kvh  = (short*)d_ws;                         // [2*NEL] bf16 (8 MB)

    cvt_kv<<<(int)(2 * NEL / (256 * 8)), 256, 0, stream>>>(k, v, kvh);
    sdpa_fused<<<NQB * BATCHES, 512, 0, stream>>>(q, kvh, kvh + NEL, out, smqk);
}

// Round 25
// 77.517 us; speedup vs baseline: 1.3816x; 1.3816x over previous
//
#include <hip/hip_runtime.h>
#include <hip/hip_bf16.h>

// SDPA, causal, b=16 t=2048 d=64. Outputs FP32: d_out = [ out | sm_qk ].
// R25 = R23 (restored best, 79.1us; R24's direct-K experiment reverted --
// scatter-pattern global frag loads are why LDS staging exists) + WIDENED
// phase-1 K staging: 16B bf16x8 loads/ds_writes (2+2 per thread per tile,
// was 4+4 x 8B). Same mechanism as R22/R23 wins: fewer, wider memory
// instructions on the round chain. Bit-identical -> absmax 0.015625.
// R23 base: prologue cvt_kv (K,V fp32->bf16 in d_ws, 8MB); 8-wave blocks;
// phase-1 KT1=128 LDS overlay; T15 pipeline; role-split staging (cvt-free);
// Q-side-compensated QK^T; fp32 Pf[2]; vectorized 1KB P-stores; lgkm-only
// barriers; mirror-band zero-fill; XCD clustering; pairing (c, 31-c).

#define BATCHES 16
#define SEQ 2048
#define DIM 64
#define QB 64
#define KT 64
#define KT1 128
#define NQB (SEQ / QB) /* 32 */
#define KLD 72
#define VLD 72
#define PFLD 68
#define NEL ((size_t)BATCHES * SEQ * DIM) /* 2M elems per tensor */

#define BAR() do { asm volatile("s_waitcnt lgkmcnt(0)" ::: "memory"); \
                   __builtin_amdgcn_s_barrier(); } while (0)

typedef __attribute__((ext_vector_type(8))) short bf16x8;
typedef __attribute__((ext_vector_type(4))) short short4v;
typedef __attribute__((ext_vector_type(4))) float f32x4;

static __device__ __forceinline__ short f2bf(float f) {
    return __builtin_bit_cast(short, __float2bfloat16(f));
}
static __device__ __forceinline__ float bf2f(short s) {
    unsigned int u = ((unsigned int)(unsigned short)s) << 16;
    return __builtin_bit_cast(float, u);
}
static __device__ __forceinline__ void split8(f32x4 a, f32x4 b, float sc,
                                              bf16x8& hh, bf16x8& ll) {
#pragma unroll
    for (int e = 0; e < 4; ++e) {
        float x = a[e] * sc; short hb = f2bf(x);
        hh[e] = hb; ll[e] = f2bf(x - bf2f(hb));
    }
#pragma unroll
    for (int e = 0; e < 4; ++e) {
        float x = b[e] * sc; short hb = f2bf(x);
        hh[4 + e] = hb; ll[4 + e] = f2bf(x - bf2f(hb));
    }
}

// ---------- prologue: K,V fp32 -> bf16 into d_ws (once) ----------
__global__ __launch_bounds__(256) void cvt_kv(
    const float* __restrict__ Kg, const float* __restrict__ Vg,
    short* __restrict__ KVh)
{
    const size_t idx = ((size_t)blockIdx.x * 256 + threadIdx.x) * 8;
    const float* src = (idx < NEL) ? (Kg + idx) : (Vg + (idx - NEL));
    f32x4 a = *(const f32x4*)src;
    f32x4 b = *(const f32x4*)(src + 4);
    bf16x8 r;
#pragma unroll
    for (int e = 0; e < 4; ++e) { r[e] = f2bf(a[e]); r[4 + e] = f2bf(b[e]); }
    *(bf16x8*)&KVh[idx] = r;
}

// LDS (bytes): Khi 18432 @0 | Vt 27648 @18432 | Pf 34816 @46080 | lS 512 @80896
// = 81408 total (2 blocks/CU). Phase-1 K1[2] 36864 overlays @0.
#define SMEM_BYTES 81408

__global__ __launch_bounds__(512, 2) void sdpa_fused(
    const float* __restrict__ Qg, const short* __restrict__ Khg,
    const short* __restrict__ Vhg, float* __restrict__ Og, float* __restrict__ Pg)
{
    const int i = blockIdx.x;
    const int g = i & 7;
    const int j = i >> 3;             // 0..63
    const int b = 2 * g + (j >> 5);
    const int jj = j & 31;
    const int qb = (j < 32) ? jj : (31 - jj);   // sum-balanced pairing
    const int q0 = qb * QB;

    const int tid = threadIdx.x;
    const int lane = tid & 63;
    const int wave = tid >> 6;        // 0..7
    const int wr = wave & 3;          // row band: rows wr*16..wr*16+15
    const int h  = wave >> 2;         // col half
    const int lo = lane & 15;
    const int hi = lane >> 4;
    const bool kStager = (wave < 4);
    const int stid = kStager ? tid : (tid - 256);
    const int sr = stid >> 4;
    const int sc_ = (stid & 15) * 4;
    const int vr = (stid >> 4) * 4;
    // phase-1 staging (all 512 threads), 16B-wide: row s1r8+64*ii, col s1c8
    const int s1r8 = tid >> 3;        // 0..63
    const int s1c8 = (tid & 7) * 8;   // 0..56

    __shared__ __align__(16) char smem[SMEM_BYTES];
    short (*Khi)[KT * KLD]  = reinterpret_cast<short (*)[KT * KLD]>(smem);            // [2]
    short (*Vt)[DIM * VLD]  = reinterpret_cast<short (*)[DIM * VLD]>(smem + 18432);   // [3]
    float (*Pf)[QB * PFLD]  = reinterpret_cast<float (*)[QB * PFLD]>(smem + 46080);   // [2]
    float (*lS)[QB]         = reinterpret_cast<float (*)[QB]>(smem + 80896);          // [2]
    short (*K1)[KT1 * KLD]  = reinterpret_cast<short (*)[KT1 * KLD]>(smem);           // [2] overlay

    const float* qB = Qg + (size_t)b * SEQ * DIM;
    const short* kB = Khg + (size_t)b * SEQ * DIM;
    const short* vB = Vhg + (size_t)b * SEQ * DIM;

    bf16x8 qa0h, qa0l, qa1h, qa1l;
    {
        const float* qr = &qB[(size_t)(q0 + wr * 16 + lo) * DIM + hi * 8];
        split8(*(const f32x4*)qr,        *(const f32x4*)(qr + 4),  0.125f, qa0h, qa0l);
        split8(*(const f32x4*)(qr + 32), *(const f32x4*)(qr + 36), 0.125f, qa1h, qa1l);
    }

    const int nkt = qb + 1;

    // mirror-band zero-fill coords: band (31-qb) of our own batch
    const int r16z = tid >> 4;        // 0..31
    const int c4z = (tid & 15) * 4;
    float* zrow0 = &Pg[((size_t)(b * SEQ) + (NQB - 1 - qb) * QB + r16z) * SEQ + c4z];
    float* zrow1 = zrow0 + (size_t)32 * SEQ;

    // ============ phase 1: l partial sums, KT1=128 per round ============
    float rl[4] = {0.f, 0.f, 0.f, 0.f};
    {
        const int nkt1 = (nkt + 1) >> 1;        // 128-wide rounds
        auto loadK1 = [&](bf16x8* kp, int t) {
#pragma unroll
            for (int ii = 0; ii < 2; ++ii)
                kp[ii] = *(const bf16x8*)&kB[(size_t)(t * KT1 + s1r8 + 64 * ii) * DIM + s1c8];
        };
        auto stageK1 = [&](int buf, const bf16x8* kp) {
#pragma unroll
            for (int ii = 0; ii < 2; ++ii)
                *(bf16x8*)&K1[buf][(s1r8 + 64 * ii) * KLD + s1c8] = kp[ii];
        };
        bf16x8 kp[2];
        loadK1(kp, 0);
        stageK1(0, kp);
        if (nkt1 > 1) loadK1(kp, 1);
        BAR();
        const int bandMax = q0 + wr * 16 + 15;  // wave-uniform
        for (int t = 0; t < nkt1; ++t) {
            const int cur = t & 1;
            if (t + 1 < nkt1) {
                stageK1(cur ^ 1, kp);
                if (t + 2 < nkt1) loadK1(kp, t + 2);
            }
            const int base = t * KT1;
#pragma unroll
            for (int nn = 0; nn < 4; ++nn) {
                const int n = 4 * h + nn;       // col group 0..7 in the 128-tile
                const int cbase = base + 16 * n;
                if (cbase > bandMax) continue;  // wave-uniform skip
                bf16x8 kh0 = *(const bf16x8*)&K1[cur][(16 * n + lo) * KLD + hi * 8];
                bf16x8 kh1 = *(const bf16x8*)&K1[cur][(16 * n + lo) * KLD + 32 + hi * 8];
                f32x4 acc = {0.f, 0.f, 0.f, 0.f};
                __builtin_amdgcn_s_setprio(1);
                acc = __builtin_amdgcn_mfma_f32_16x16x32_bf16(qa0h, kh0, acc, 0, 0, 0);
                acc = __builtin_amdgcn_mfma_f32_16x16x32_bf16(qa1h, kh1, acc, 0, 0, 0);
                __builtin_amdgcn_s_setprio(0);
                if (cbase + 15 <= q0 + wr * 16) {   // fully unmasked (wave-uniform)
#pragma unroll
                    for (int jx = 0; jx < 4; ++jx) rl[jx] += __expf(acc[jx]);
                } else {
                    const int col = cbase + lo;
#pragma unroll
                    for (int jx = 0; jx < 4; ++jx)
                        if (col <= q0 + wr * 16 + hi * 4 + jx) rl[jx] += __expf(acc[jx]);
                }
            }
            BAR();
        }
    }
    // merge the two col-half partials -> il
#pragma unroll
    for (int m = 1; m <= 8; m <<= 1)
#pragma unroll
        for (int jx = 0; jx < 4; ++jx) rl[jx] += __shfl_xor(rl[jx], m, 16);
    if (lo == 0) {
#pragma unroll
        for (int jx = 0; jx < 4; ++jx)
            lS[h][wr * 16 + hi * 4 + jx] = rl[jx];
    }
    BAR();
    float il[4];
#pragma unroll
    for (int jx = 0; jx < 4; ++jx) {
        const int row = wr * 16 + hi * 4 + jx;
        il[jx] = 1.0f / (lS[0][row] + lS[1][row]);
    }
    BAR();   // all waves done reading lS before phase 2 overwrites smem

    // ===== phase 2: P -> Pf (fp32 LDS), vectorized row-store + PV pipelined ==
    const int n0 = 2 * h;
    f32x4 o2[2];
#pragma unroll
    for (int nn = 0; nn < 2; ++nn) { o2[nn][0] = 0.f; o2[nn][1] = 0.f; o2[nn][2] = 0.f; o2[nn][3] = 0.f; }

    auto loadK = [&](short4v* kp, int kt) {
#pragma unroll
        for (int ii = 0; ii < 4; ++ii)
            kp[ii] = *(const short4v*)&kB[(size_t)(kt * KT + sr + 16 * ii) * DIM + sc_];
    };
    auto loadV = [&](short4v* vp, int kt) {
#pragma unroll
        for (int ii = 0; ii < 4; ++ii)
            vp[ii] = *(const short4v*)&vB[(size_t)(kt * KT + vr + ii) * DIM + sc_];
    };
    auto stageKhi = [&](int buf, const short4v* kp) {
#pragma unroll
        for (int ii = 0; ii < 4; ++ii)
            *(short4v*)&Khi[buf][(sr + 16 * ii) * KLD + sc_] = kp[ii];
    };
    auto stageVt = [&](int buf, const short4v* vp) {
#pragma unroll
        for (int e = 0; e < 4; ++e) {   // 4x4 register transpose, no cvt
            short4v tv;
#pragma unroll
            for (int ii = 0; ii < 4; ++ii) tv[ii] = vp[ii][e];
            *(short4v*)&Vt[buf][(sc_ + e) * VLD + vr] = tv;
        }
    };
    // VECTORIZED P row-store: lane covers rows wave*8+{rr,rr+4}, 16B each
    auto rowStore = [&](int pbuf, int kt) {
        const int rr = lane >> 4;          // 0..3
        const int cc = (lane & 15) * 4;    // 16B-aligned col offset
        float* dst0 = &Pg[((size_t)(b * SEQ) + q0 + wave * 8 + rr) * SEQ + kt * KT + cc];
        *(f32x4*)dst0 = *(const f32x4*)&Pf[pbuf][(wave * 8 + rr) * PFLD + cc];
        *(f32x4*)(dst0 + (size_t)4 * SEQ) =
            *(const f32x4*)&Pf[pbuf][(wave * 8 + 4 + rr) * PFLD + cc];
    };
    // PV from Pf[pbuf] (fp32 -> bf16 frags) against Vt[vbuf]
    auto pvStep = [&](int pbuf, int vbuf) {
        const float* pr = &Pf[pbuf][(wr * 16 + lo) * PFLD + hi * 8];
        f32x4 a = *(const f32x4*)pr, c2 = *(const f32x4*)(pr + 4);
        f32x4 d = *(const f32x4*)(pr + 32), e2 = *(const f32x4*)(pr + 36);
        bf16x8 pa0, pa1;
#pragma unroll
        for (int e = 0; e < 4; ++e) {
            pa0[e] = f2bf(a[e]); pa0[4 + e] = f2bf(c2[e]);
            pa1[e] = f2bf(d[e]); pa1[4 + e] = f2bf(e2[e]);
        }
        __builtin_amdgcn_s_setprio(1);
#pragma unroll
        for (int nn = 0; nn < 2; ++nn) {
            const int n = n0 + nn;
            bf16x8 vb0 = *(const bf16x8*)&Vt[vbuf][(16 * n + lo) * VLD + hi * 8];
            bf16x8 vb1 = *(const bf16x8*)&Vt[vbuf][(16 * n + lo) * VLD + 32 + hi * 8];
            o2[nn] = __builtin_amdgcn_mfma_f32_16x16x32_bf16(pa0, vb0, o2[nn], 0, 0, 0);
            o2[nn] = __builtin_amdgcn_mfma_f32_16x16x32_bf16(pa1, vb1, o2[nn], 0, 0, 0);
        }
        __builtin_amdgcn_s_setprio(0);
    };

    {
        short4v kp[4], vp[4];
        if (kStager) {
            loadK(kp, 0); stageKhi(0, kp);
            if (nkt > 1) loadK(kp, 1);
        } else {
            loadV(vp, 0); stageVt(0, vp);
            if (nkt > 1) loadV(vp, 1);
        }
        BAR();

        int vstg = 1, vprev = 2;
        for (int kt = 0; kt < nkt; ++kt) {
            const int cur = kt & 1;
            const int pcur = kt & 1;
            // mirror-band zero tile (1/round, kt<qb): 2 dwordx4/thread
            if (kt < qb) {
                const int zt = (NQB - qb) + kt;
                const f32x4 zv = {0.f, 0.f, 0.f, 0.f};
                *(f32x4*)&zrow0[zt * KT] = zv;
                *(f32x4*)&zrow1[zt * KT] = zv;
            }
            if (kt + 1 < nkt) {
                if (kStager) {
                    stageKhi(cur ^ 1, kp);
                    if (kt + 2 < nkt) loadK(kp, kt + 2);
                } else {
                    stageVt(vstg, vp);
                    if (kt + 2 < nkt) loadV(vp, kt + 2);
                }
            }
            // ---- tile kt-1: vectorized row-store + PV (inputs ready at start)
            if (kt > 0) {
                rowStore(pcur ^ 1, kt - 1);
                pvStep(pcur ^ 1, vprev);
            }
            // ---- QKT(kt) (Q-side compensated): P = exp(S)*il -> Pf[pcur] ----
#pragma unroll
            for (int nn = 0; nn < 2; ++nn) {
                const int n = n0 + nn;
                const bool fm = (kt == qb) && (n > wr);   // wave-uniform
                f32x4 acc = {0.f, 0.f, 0.f, 0.f};
                if (!fm) {
                    bf16x8 kh0 = *(const bf16x8*)&Khi[cur][(16 * n + lo) * KLD + hi * 8];
                    bf16x8 kh1 = *(const bf16x8*)&Khi[cur][(16 * n + lo) * KLD + 32 + hi * 8];
                    __builtin_amdgcn_s_setprio(1);
                    acc = __builtin_amdgcn_mfma_f32_16x16x32_bf16(qa0h, kh0, acc, 0, 0, 0);
                    acc = __builtin_amdgcn_mfma_f32_16x16x32_bf16(qa1h, kh1, acc, 0, 0, 0);
                    acc = __builtin_amdgcn_mfma_f32_16x16x32_bf16(qa0l, kh0, acc, 0, 0, 0);
                    acc = __builtin_amdgcn_mfma_f32_16x16x32_bf16(qa1l, kh1, acc, 0, 0, 0);
                    __builtin_amdgcn_s_setprio(0);
                }
                const int col = 16 * n + lo;
#pragma unroll
                for (int jx = 0; jx < 4; ++jx) {
                    const int row = wr * 16 + hi * 4 + jx;
                    const float p = (!fm && (kt < qb || col <= row)) ? __expf(acc[jx]) * il[jx] : 0.f;
                    Pf[pcur][row * PFLD + col] = p;
                }
            }
            BAR();
            vprev = (vprev == 2) ? 0 : vprev + 1;
            vstg  = (vstg  == 2) ? 0 : vstg  + 1;
        }
        // ---- epilogue: tile nkt-1 store + PV (after the loop's final BAR) ----
        {
            const int pl = (nkt - 1) & 1;
            const int vl = (nkt - 1) % 3;
            rowStore(pl, nkt - 1);
            pvStep(pl, vl);
        }
    }

    // ---- O (already normalized; own col half), fp32 ----
    {
        float* og = &Og[((size_t)(b * SEQ) + q0 + wr * 16 + hi * 4) * DIM + lo];
#pragma unroll
        for (int jx = 0; jx < 4; ++jx)
#pragma unroll
            for (int nn = 0; nn < 2; ++nn)
                og[jx * DIM + (n0 + nn) * 16] = o2[nn][jx];
    }
}

extern "C" void kernel_launch(void* const* d_in, const int* in_sizes, int n_in,
                              void* d_out, int out_size, void* d_ws, size_t ws_size,
                              hipStream_t stream) {
    const float* q = (const float*)d_in[0];
    const float* k = (const float*)d_in[1];
    const float* v = (const float*)d_in[2];
    float* out  = (float*)d_out;                        // [B,T,D] fp32
    float* smqk = out + (size_t)BATCHES * SEQ * DIM;    // [B,T,T] fp32
    short* kvh  = (short*)d_ws;                         // [2*NEL] bf16 (8 MB)

    cvt_kv<<<(int)(2 * NEL / (256 * 8)), 256, 0, stream>>>(k, v, kvh);
    sdpa_fused<<<NQB * BATCHES, 512, 0, stream>>>(q, kvh, kvh + NEL, out, smqk);
}

// Round 26
// 76.767 us; speedup vs baseline: 1.3951x; 1.0098x over previous
//
#include <hip/hip_runtime.h>
#include <hip/hip_bf16.h>

// SDPA, causal, b=16 t=2048 d=64. Outputs FP32: d_out = [ out | sm_qk ].
// R26 = R25 + phase-2 K staging widened to 16B bf16x8 (2 loads + 2 ds_writes
// per stager thread per tile, was 4+4 x 8B) -- same proven mechanism as
// R22/R23/R25 (fewer, wider memory instructions on the round chain).
// Bit-identical -> absmax must stay exactly 0.015625.
// Base: prologue cvt_kv (K,V fp32->bf16 in d_ws, 8MB); 8-wave blocks;
// phase-1 KT1=128 LDS overlay w/ 16B staging; T15 pipeline; role-split
// staging (cvt-free); Q-side-compensated QK^T; fp32 Pf[2]; vectorized 1KB
// P-stores; lgkm-only barriers; mirror-band zero-fill; XCD clustering;
// pairing (c, 31-c).

#define BATCHES 16
#define SEQ 2048
#define DIM 64
#define QB 64
#define KT 64
#define KT1 128
#define NQB (SEQ / QB) /* 32 */
#define KLD 72
#define VLD 72
#define PFLD 68
#define NEL ((size_t)BATCHES * SEQ * DIM) /* 2M elems per tensor */

#define BAR() do { asm volatile("s_waitcnt lgkmcnt(0)" ::: "memory"); \
                   __builtin_amdgcn_s_barrier(); } while (0)

typedef __attribute__((ext_vector_type(8))) short bf16x8;
typedef __attribute__((ext_vector_type(4))) short short4v;
typedef __attribute__((ext_vector_type(4))) float f32x4;

static __device__ __forceinline__ short f2bf(float f) {
    return __builtin_bit_cast(short, __float2bfloat16(f));
}
static __device__ __forceinline__ float bf2f(short s) {
    unsigned int u = ((unsigned int)(unsigned short)s) << 16;
    return __builtin_bit_cast(float, u);
}
static __device__ __forceinline__ void split8(f32x4 a, f32x4 b, float sc,
                                              bf16x8& hh, bf16x8& ll) {
#pragma unroll
    for (int e = 0; e < 4; ++e) {
        float x = a[e] * sc; short hb = f2bf(x);
        hh[e] = hb; ll[e] = f2bf(x - bf2f(hb));
    }
#pragma unroll
    for (int e = 0; e < 4; ++e) {
        float x = b[e] * sc; short hb = f2bf(x);
        hh[4 + e] = hb; ll[4 + e] = f2bf(x - bf2f(hb));
    }
}

// ---------- prologue: K,V fp32 -> bf16 into d_ws (once) ----------
__global__ __launch_bounds__(256) void cvt_kv(
    const float* __restrict__ Kg, const float* __restrict__ Vg,
    short* __restrict__ KVh)
{
    const size_t idx = ((size_t)blockIdx.x * 256 + threadIdx.x) * 8;
    const float* src = (idx < NEL) ? (Kg + idx) : (Vg + (idx - NEL));
    f32x4 a = *(const f32x4*)src;
    f32x4 b = *(const f32x4*)(src + 4);
    bf16x8 r;
#pragma unroll
    for (int e = 0; e < 4; ++e) { r[e] = f2bf(a[e]); r[4 + e] = f2bf(b[e]); }
    *(bf16x8*)&KVh[idx] = r;
}

// LDS (bytes): Khi 18432 @0 | Vt 27648 @18432 | Pf 34816 @46080 | lS 512 @80896
// = 81408 total (2 blocks/CU). Phase-1 K1[2] 36864 overlays @0.
#define SMEM_BYTES 81408

__global__ __launch_bounds__(512, 2) void sdpa_fused(
    const float* __restrict__ Qg, const short* __restrict__ Khg,
    const short* __restrict__ Vhg, float* __restrict__ Og, float* __restrict__ Pg)
{
    const int i = blockIdx.x;
    const int g = i & 7;
    const int j = i >> 3;             // 0..63
    const int b = 2 * g + (j >> 5);
    const int jj = j & 31;
    const int qb = (j < 32) ? jj : (31 - jj);   // sum-balanced pairing
    const int q0 = qb * QB;

    const int tid = threadIdx.x;
    const int lane = tid & 63;
    const int wave = tid >> 6;        // 0..7
    const int wr = wave & 3;          // row band: rows wr*16..wr*16+15
    const int h  = wave >> 2;         // col half
    const int lo = lane & 15;
    const int hi = lane >> 4;
    const bool kStager = (wave < 4);
    const int stid = kStager ? tid : (tid - 256);
    const int sc_ = (stid & 15) * 4;
    const int vr = (stid >> 4) * 4;
    // phase-2 K staging, 16B-wide: rows s2r8+32*ii (ii<2), col s2c8
    const int s2r8 = stid >> 3;       // 0..31
    const int s2c8 = (stid & 7) * 8;  // 0..56
    // phase-1 staging (all 512 threads), 16B-wide: row s1r8+64*ii, col s1c8
    const int s1r8 = tid >> 3;        // 0..63
    const int s1c8 = (tid & 7) * 8;   // 0..56

    __shared__ __align__(16) char smem[SMEM_BYTES];
    short (*Khi)[KT * KLD]  = reinterpret_cast<short (*)[KT * KLD]>(smem);            // [2]
    short (*Vt)[DIM * VLD]  = reinterpret_cast<short (*)[DIM * VLD]>(smem + 18432);   // [3]
    float (*Pf)[QB * PFLD]  = reinterpret_cast<float (*)[QB * PFLD]>(smem + 46080);   // [2]
    float (*lS)[QB]         = reinterpret_cast<float (*)[QB]>(smem + 80896);          // [2]
    short (*K1)[KT1 * KLD]  = reinterpret_cast<short (*)[KT1 * KLD]>(smem);           // [2] overlay

    const float* qB = Qg + (size_t)b * SEQ * DIM;
    const short* kB = Khg + (size_t)b * SEQ * DIM;
    const short* vB = Vhg + (size_t)b * SEQ * DIM;

    bf16x8 qa0h, qa0l, qa1h, qa1l;
    {
        const float* qr = &qB[(size_t)(q0 + wr * 16 + lo) * DIM + hi * 8];
        split8(*(const f32x4*)qr,        *(const f32x4*)(qr + 4),  0.125f, qa0h, qa0l);
        split8(*(const f32x4*)(qr + 32), *(const f32x4*)(qr + 36), 0.125f, qa1h, qa1l);
    }

    const int nkt = qb + 1;

    // mirror-band zero-fill coords: band (31-qb) of our own batch
    const int r16z = tid >> 4;        // 0..31
    const int c4z = (tid & 15) * 4;
    float* zrow0 = &Pg[((size_t)(b * SEQ) + (NQB - 1 - qb) * QB + r16z) * SEQ + c4z];
    float* zrow1 = zrow0 + (size_t)32 * SEQ;

    // ============ phase 1: l partial sums, KT1=128 per round ============
    float rl[4] = {0.f, 0.f, 0.f, 0.f};
    {
        const int nkt1 = (nkt + 1) >> 1;        // 128-wide rounds
        auto loadK1 = [&](bf16x8* kp, int t) {
#pragma unroll
            for (int ii = 0; ii < 2; ++ii)
                kp[ii] = *(const bf16x8*)&kB[(size_t)(t * KT1 + s1r8 + 64 * ii) * DIM + s1c8];
        };
        auto stageK1 = [&](int buf, const bf16x8* kp) {
#pragma unroll
            for (int ii = 0; ii < 2; ++ii)
                *(bf16x8*)&K1[buf][(s1r8 + 64 * ii) * KLD + s1c8] = kp[ii];
        };
        bf16x8 kp[2];
        loadK1(kp, 0);
        stageK1(0, kp);
        if (nkt1 > 1) loadK1(kp, 1);
        BAR();
        const int bandMax = q0 + wr * 16 + 15;  // wave-uniform
        for (int t = 0; t < nkt1; ++t) {
            const int cur = t & 1;
            if (t + 1 < nkt1) {
                stageK1(cur ^ 1, kp);
                if (t + 2 < nkt1) loadK1(kp, t + 2);
            }
            const int base = t * KT1;
#pragma unroll
            for (int nn = 0; nn < 4; ++nn) {
                const int n = 4 * h + nn;       // col group 0..7 in the 128-tile
                const int cbase = base + 16 * n;
                if (cbase > bandMax) continue;  // wave-uniform skip
                bf16x8 kh0 = *(const bf16x8*)&K1[cur][(16 * n + lo) * KLD + hi * 8];
                bf16x8 kh1 = *(const bf16x8*)&K1[cur][(16 * n + lo) * KLD + 32 + hi * 8];
                f32x4 acc = {0.f, 0.f, 0.f, 0.f};
                __builtin_amdgcn_s_setprio(1);
                acc = __builtin_amdgcn_mfma_f32_16x16x32_bf16(qa0h, kh0, acc, 0, 0, 0);
                acc = __builtin_amdgcn_mfma_f32_16x16x32_bf16(qa1h, kh1, acc, 0, 0, 0);
                __builtin_amdgcn_s_setprio(0);
                if (cbase + 15 <= q0 + wr * 16) {   // fully unmasked (wave-uniform)
#pragma unroll
                    for (int jx = 0; jx < 4; ++jx) rl[jx] += __expf(acc[jx]);
                } else {
                    const int col = cbase + lo;
#pragma unroll
                    for (int jx = 0; jx < 4; ++jx)
                        if (col <= q0 + wr * 16 + hi * 4 + jx) rl[jx] += __expf(acc[jx]);
                }
            }
            BAR();
        }
    }
    // merge the two col-half partials -> il
#pragma unroll
    for (int m = 1; m <= 8; m <<= 1)
#pragma unroll
        for (int jx = 0; jx < 4; ++jx) rl[jx] += __shfl_xor(rl[jx], m, 16);
    if (lo == 0) {
#pragma unroll
        for (int jx = 0; jx < 4; ++jx)
            lS[h][wr * 16 + hi * 4 + jx] = rl[jx];
    }
    BAR();
    float il[4];
#pragma unroll
    for (int jx = 0; jx < 4; ++jx) {
        const int row = wr * 16 + hi * 4 + jx;
        il[jx] = 1.0f / (lS[0][row] + lS[1][row]);
    }
    BAR();   // all waves done reading lS before phase 2 overwrites smem

    // ===== phase 2: P -> Pf (fp32 LDS), vectorized row-store + PV pipelined ==
    const int n0 = 2 * h;
    f32x4 o2[2];
#pragma unroll
    for (int nn = 0; nn < 2; ++nn) { o2[nn][0] = 0.f; o2[nn][1] = 0.f; o2[nn][2] = 0.f; o2[nn][3] = 0.f; }

    auto loadK = [&](bf16x8* kp, int kt) {
#pragma unroll
        for (int ii = 0; ii < 2; ++ii)
            kp[ii] = *(const bf16x8*)&kB[(size_t)(kt * KT + s2r8 + 32 * ii) * DIM + s2c8];
    };
    auto loadV = [&](short4v* vp, int kt) {
#pragma unroll
        for (int ii = 0; ii < 4; ++ii)
            vp[ii] = *(const short4v*)&vB[(size_t)(kt * KT + vr + ii) * DIM + sc_];
    };
    auto stageKhi = [&](int buf, const bf16x8* kp) {
#pragma unroll
        for (int ii = 0; ii < 2; ++ii)
            *(bf16x8*)&Khi[buf][(s2r8 + 32 * ii) * KLD + s2c8] = kp[ii];
    };
    auto stageVt = [&](int buf, const short4v* vp) {
#pragma unroll
        for (int e = 0; e < 4; ++e) {   // 4x4 register transpose, no cvt
            short4v tv;
#pragma unroll
            for (int ii = 0; ii < 4; ++ii) tv[ii] = vp[ii][e];
            *(short4v*)&Vt[buf][(sc_ + e) * VLD + vr] = tv;
        }
    };
    // VECTORIZED P row-store: lane covers rows wave*8+{rr,rr+4}, 16B each
    auto rowStore = [&](int pbuf, int kt) {
        const int rr = lane >> 4;          // 0..3
        const int cc = (lane & 15) * 4;    // 16B-aligned col offset
        float* dst0 = &Pg[((size_t)(b * SEQ) + q0 + wave * 8 + rr) * SEQ + kt * KT + cc];
        *(f32x4*)dst0 = *(const f32x4*)&Pf[pbuf][(wave * 8 + rr) * PFLD + cc];
        *(f32x4*)(dst0 + (size_t)4 * SEQ) =
            *(const f32x4*)&Pf[pbuf][(wave * 8 + 4 + rr) * PFLD + cc];
    };
    // PV from Pf[pbuf] (fp32 -> bf16 frags) against Vt[vbuf]
    auto pvStep = [&](int pbuf, int vbuf) {
        const float* pr = &Pf[pbuf][(wr * 16 + lo) * PFLD + hi * 8];
        f32x4 a = *(const f32x4*)pr, c2 = *(const f32x4*)(pr + 4);
        f32x4 d = *(const f32x4*)(pr + 32), e2 = *(const f32x4*)(pr + 36);
        bf16x8 pa0, pa1;
#pragma unroll
        for (int e = 0; e < 4; ++e) {
            pa0[e] = f2bf(a[e]); pa0[4 + e] = f2bf(c2[e]);
            pa1[e] = f2bf(d[e]); pa1[4 + e] = f2bf(e2[e]);
        }
        __builtin_amdgcn_s_setprio(1);
#pragma unroll
        for (int nn = 0; nn < 2; ++nn) {
            const int n = n0 + nn;
            bf16x8 vb0 = *(const bf16x8*)&Vt[vbuf][(16 * n + lo) * VLD + hi * 8];
            bf16x8 vb1 = *(const bf16x8*)&Vt[vbuf][(16 * n + lo) * VLD + 32 + hi * 8];
            o2[nn] = __builtin_amdgcn_mfma_f32_16x16x32_bf16(pa0, vb0, o2[nn], 0, 0, 0);
            o2[nn] = __builtin_amdgcn_mfma_f32_16x16x32_bf16(pa1, vb1, o2[nn], 0, 0, 0);
        }
        __builtin_amdgcn_s_setprio(0);
    };

    {
        bf16x8 kp[2];
        short4v vp[4];
        if (kStager) {
            loadK(kp, 0); stageKhi(0, kp);
            if (nkt > 1) loadK(kp, 1);
        } else {
            loadV(vp, 0); stageVt(0, vp);
            if (nkt > 1) loadV(vp, 1);
        }
        BAR();

        int vstg = 1, vprev = 2;
        for (int kt = 0; kt < nkt; ++kt) {
            const int cur = kt & 1;
            const int pcur = kt & 1;
            // mirror-band zero tile (1/round, kt<qb): 2 dwordx4/thread
            if (kt < qb) {
                const int zt = (NQB - qb) + kt;
                const f32x4 zv = {0.f, 0.f, 0.f, 0.f};
                *(f32x4*)&zrow0[zt * KT] = zv;
                *(f32x4*)&zrow1[zt * KT] = zv;
            }
            if (kt + 1 < nkt) {
                if (kStager) {
                    stageKhi(cur ^ 1, kp);
                    if (kt + 2 < nkt) loadK(kp, kt + 2);
                } else {
                    stageVt(vstg, vp);
                    if (kt + 2 < nkt) loadV(vp, kt + 2);
                }
            }
            // ---- tile kt-1: vectorized row-store + PV (inputs ready at start)
            if (kt > 0) {
                rowStore(pcur ^ 1, kt - 1);
                pvStep(pcur ^ 1, vprev);
            }
            // ---- QKT(kt) (Q-side compensated): P = exp(S)*il -> Pf[pcur] ----
#pragma unroll
            for (int nn = 0; nn < 2; ++nn) {
                const int n = n0 + nn;
                const bool fm = (kt == qb) && (n > wr);   // wave-uniform
                f32x4 acc = {0.f, 0.f, 0.f, 0.f};
                if (!fm) {
                    bf16x8 kh0 = *(const bf16x8*)&Khi[cur][(16 * n + lo) * KLD + hi * 8];
                    bf16x8 kh1 = *(const bf16x8*)&Khi[cur][(16 * n + lo) * KLD + 32 + hi * 8];
                    __builtin_amdgcn_s_setprio(1);
                    acc = __builtin_amdgcn_mfma_f32_16x16x32_bf16(qa0h, kh0, acc, 0, 0, 0);
                    acc = __builtin_amdgcn_mfma_f32_16x16x32_bf16(qa1h, kh1, acc, 0, 0, 0);
                    acc = __builtin_amdgcn_mfma_f32_16x16x32_bf16(qa0l, kh0, acc, 0, 0, 0);
                    acc = __builtin_amdgcn_mfma_f32_16x16x32_bf16(qa1l, kh1, acc, 0, 0, 0);
                    __builtin_amdgcn_s_setprio(0);
                }
                const int col = 16 * n + lo;
#pragma unroll
                for (int jx = 0; jx < 4; ++jx) {
                    const int row = wr * 16 + hi * 4 + jx;
                    const float p = (!fm && (kt < qb || col <= row)) ? __expf(acc[jx]) * il[jx] : 0.f;
                    Pf[pcur][row * PFLD + col] = p;
                }
            }
            BAR();
            vprev = (vprev == 2) ? 0 : vprev + 1;
            vstg  = (vstg  == 2) ? 0 : vstg  + 1;
        }
        // ---- epilogue: tile nkt-1 store + PV (after the loop's final BAR) ----
        {
            const int pl = (nkt - 1) & 1;
            const int vl = (nkt - 1) % 3;
            rowStore(pl, nkt - 1);
            pvStep(pl, vl);
        }
    }

    // ---- O (already normalized; own col half), fp32 ----
    {
        float* og = &Og[((size_t)(b * SEQ) + q0 + wr * 16 + hi * 4) * DIM + lo];
#pragma unroll
        for (int jx = 0; jx < 4; ++jx)
#pragma unroll
            for (int nn = 0; nn < 2; ++nn)
                og[jx * DIM + (n0 + nn) * 16] = o2[nn][jx];
    }
}

extern "C" void kernel_launch(void* const* d_in, const int* in_sizes, int n_in,
                              void* d_out, int out_size, void* d_ws, size_t ws_size,
                              hipStream_t stream) {
    const float* q = (const float*)d_in[0];
    const float* k = (const float*)d_in[1];
    const float* v = (const float*)d_in[2];
    float* out  = (float*)d_out;                        // [B,T,D] fp32
    float* smqk = out + (size_t)BATCHES * SEQ * DIM;    // [B,T,T] fp32
    short* kvh  = (short*)d_ws;                         // [2*NEL] bf16 (8 MB)

    cvt_kv<<<(int)(2 * NEL / (256 * 8)), 256, 0, stream>>>(k, v, kvh);
    sdpa_fused<<<NQB * BATCHES, 512, 0, stream>>>(q, kvh, kvh + NEL, out, smqk);
}